// Round 1
// baseline (1354.312 us; speedup 1.0000x reference)
//
#include <hip/hip_runtime.h>

// FlashACE: 2-layer edge-MLP message passing + node update, N=50000, E=1.6M, HID=128.
// Key restructuring:
//   msgs = silu([S[s],S[r],len] @ w1 + b1) @ w2 + b2 ; agg = segsum(msgs, r)
//   =>  Xs = S@w1[0:128], Xrb = S@w1[128:256] + b1          (node GEMMs)
//       P[r] = sum_e silu(Xs[s_e] + Xrb[r] + len_e*w1[256]) (edge pass, CSR, no atomics on P)
//       S += P@w2 + deg*b2                                  (node GEMM)
// Total GEMM work drops 320 GF -> ~13 GF.

#define NFEAT 224
#define HID 128

__device__ __forceinline__ float silu_f(float x) {
    float e = __expf(-x);
    return x * __builtin_amdgcn_rcpf(1.0f + e);
}

// ---------------- split: h -> S (first 128 cols), rest -> d_out cols 128..223
__global__ void k_split(const float* __restrict__ h, float* __restrict__ S,
                        float* __restrict__ out, int N) {
    int n = blockIdx.x;
    int j = threadIdx.x;
    if (n >= N || j >= NFEAT) return;
    float v = h[(size_t)n * NFEAT + j];
    if (j < HID) S[(size_t)n * HID + j] = v;
    else out[(size_t)n * NFEAT + j] = v;
}

// ---------------- CSR build
__global__ void k_deg(const int* __restrict__ recv, int* __restrict__ deg, int E) {
    int i = blockIdx.x * blockDim.x + threadIdx.x;
    if (i < E) atomicAdd(&deg[recv[i]], 1);
}

__global__ void k_scan(const int* __restrict__ deg, int* __restrict__ rowstart, int N) {
    // single block, 1024 threads
    __shared__ int ps[1024];
    int t = threadIdx.x;
    int C = (N + 1023) / 1024;
    int lo = t * C;
    int hi = lo + C; if (hi > N) hi = N;
    int s = 0;
    for (int i = lo; i < hi; ++i) s += deg[i];
    ps[t] = s;
    __syncthreads();
    for (int off = 1; off < 1024; off <<= 1) {
        int add = (t >= off) ? ps[t - off] : 0;
        __syncthreads();
        ps[t] += add;
        __syncthreads();
    }
    int run = (t == 0) ? 0 : ps[t - 1];
    for (int i = lo; i < hi; ++i) { rowstart[i] = run; run += deg[i]; }
    if (t == 1023) rowstart[N] = ps[1023];
}

__global__ void k_scatter(const int* __restrict__ recv, int* __restrict__ cursor,
                          int* __restrict__ elist, int E) {
    int i = blockIdx.x * blockDim.x + threadIdx.x;
    if (i < E) {
        int pos = atomicAdd(&cursor[recv[i]], 1);
        elist[pos] = i;
    }
}

// ---------------- fp32 GEMM, fixed K=N=128. C[M,128] = op(A[M,128] @ W[128,128] + bias*scale)
// BM=64, threads=256, microtile 8 rows x 4 cols per thread.
template <int ACC, int SILU>
__launch_bounds__(256)
__global__ void gemm128(const float* __restrict__ A, const float* __restrict__ W,
                        const float* __restrict__ bias, const int* __restrict__ rowscale,
                        float* __restrict__ C, int M) {
    __shared__ float As[64][20];    // +4 pad, keeps 16B alignment (20*4=80B)
    __shared__ float Ws[16][128];
    const int tid = threadIdx.x;
    const int tx = tid & 31;        // col group: 4 cols
    const int ty = tid >> 5;        // row group: 8 rows
    const int row0 = blockIdx.x * 64;
    const int j0 = tx * 4;
    const int i0 = ty * 8;
    float acc[8][4];
#pragma unroll
    for (int r = 0; r < 8; ++r)
#pragma unroll
        for (int c = 0; c < 4; ++c) acc[r][c] = 0.0f;

    for (int kc = 0; kc < 128; kc += 16) {
        __syncthreads();
        {   // stage A chunk 64x16
            int r = tid >> 2;
            int kq = (tid & 3) * 4;
            int gr = row0 + r;
            float4 v = make_float4(0.f, 0.f, 0.f, 0.f);
            if (gr < M) v = *(const float4*)(A + (size_t)gr * 128 + kc + kq);
            *(float4*)(&As[r][kq]) = v;
        }
        {   // stage W chunk 16x128
#pragma unroll
            for (int q = tid; q < 512; q += 256) {
                int r = q >> 5;
                int c4 = (q & 31) * 4;
                *(float4*)(&Ws[r][c4]) = *(const float4*)(W + (size_t)(kc + r) * 128 + c4);
            }
        }
        __syncthreads();
#pragma unroll
        for (int k4 = 0; k4 < 16; k4 += 4) {
            float4 b0 = *(const float4*)(&Ws[k4 + 0][j0]);
            float4 b1 = *(const float4*)(&Ws[k4 + 1][j0]);
            float4 b2 = *(const float4*)(&Ws[k4 + 2][j0]);
            float4 b3 = *(const float4*)(&Ws[k4 + 3][j0]);
#pragma unroll
            for (int r = 0; r < 8; ++r) {
                float4 a = *(const float4*)(&As[i0 + r][k4]);   // broadcast across 32 lanes
                acc[r][0] += a.x * b0.x + a.y * b1.x + a.z * b2.x + a.w * b3.x;
                acc[r][1] += a.x * b0.y + a.y * b1.y + a.z * b2.y + a.w * b3.y;
                acc[r][2] += a.x * b0.z + a.y * b1.z + a.z * b2.z + a.w * b3.z;
                acc[r][3] += a.x * b0.w + a.y * b1.w + a.z * b2.w + a.w * b3.w;
            }
        }
    }

#pragma unroll
    for (int r = 0; r < 8; ++r) {
        int gr = row0 + i0 + r;
        if (gr >= M) continue;
        float sc = 1.0f;
        if (rowscale) sc = (float)rowscale[gr];
#pragma unroll
        for (int c = 0; c < 4; ++c) {
            int j = j0 + c;
            float v = acc[r][c];
            if (bias) v += bias[j] * sc;
            if (SILU) v = silu_f(v);
            size_t idx = (size_t)gr * 128 + j;
            if (ACC) C[idx] = C[idx] + v;
            else C[idx] = v;
        }
    }
}

// ---------------- edge aggregation: one wave (64 lanes) per receiver node, float2/lane
__launch_bounds__(256)
__global__ void k_edge(const float* __restrict__ Xs, const float* __restrict__ Xrb,
                       const float* __restrict__ w1L, const float* __restrict__ elen,
                       const int* __restrict__ sender, const int* __restrict__ elist,
                       const int* __restrict__ rowstart, float* __restrict__ P, int N) {
    int wid = (blockIdx.x * blockDim.x + threadIdx.x) >> 6;
    int lane = threadIdx.x & 63;
    if (wid >= N) return;
    int j = lane * 2;
    float2 xr = *(const float2*)(Xrb + (size_t)wid * 128 + j);
    float2 wl = *(const float2*)(w1L + j);
    float ax = 0.f, ay = 0.f;
    int lo = rowstart[wid], hi = rowstart[wid + 1];
    for (int i = lo; i < hi; ++i) {
        int e = elist[i];
        int s = sender[e];
        float len = elen[e];
        float2 xs = *(const float2*)(Xs + (size_t)s * 128 + j);
        float px = xs.x + xr.x + len * wl.x;
        float py = xs.y + xr.y + len * wl.y;
        ax += silu_f(px);
        ay += silu_f(py);
    }
    *(float2*)(P + (size_t)wid * 128 + j) = make_float2(ax, ay);
}

// ---------------- final: d_out[:, :128] = S + U
__global__ void k_final(const float* __restrict__ S, const float* __restrict__ U,
                        float* __restrict__ out, int N) {
    int n = blockIdx.x;
    int j = threadIdx.x;
    if (n >= N || j >= HID) return;
    size_t si = (size_t)n * 128 + j;
    out[(size_t)n * NFEAT + j] = S[si] + U[si];
}

extern "C" void kernel_launch(void* const* d_in, const int* in_sizes, int n_in,
                              void* d_out, int out_size, void* d_ws, size_t ws_size,
                              hipStream_t stream) {
    const float* h      = (const float*)d_in[0];
    const int*   eidx   = (const int*)d_in[1];
    const float* elen   = (const float*)d_in[2];
    const float* mp_w1  = (const float*)d_in[3];
    const float* mp_b1  = (const float*)d_in[4];
    const float* mp_w2  = (const float*)d_in[5];
    const float* mp_b2  = (const float*)d_in[6];
    const float* nu_w1  = (const float*)d_in[7];
    const float* nu_b1  = (const float*)d_in[8];
    const float* nu_w2  = (const float*)d_in[9];
    const float* nu_b2  = (const float*)d_in[10];
    float* out = (float*)d_out;

    const int N = in_sizes[0] / NFEAT;   // 50000
    const int E = in_sizes[2];           // 1600000
    const int* sender   = eidx;
    const int* receiver = eidx + E;

    // workspace carve-out (~110 MB)
    char* w = (char*)d_ws;
    auto alloc = [&](size_t bytes) -> char* {
        char* p = w;
        w += (bytes + 255) & ~(size_t)255;
        return p;
    };
    float* S        = (float*)alloc((size_t)N * 128 * 4);
    float* Xs       = (float*)alloc((size_t)N * 128 * 4);
    float* Xrb      = (float*)alloc((size_t)N * 128 * 4);
    float* P        = (float*)alloc((size_t)N * 128 * 4);
    int*   deg      = (int*)alloc((size_t)N * 4);
    int*   rowstart = (int*)alloc((size_t)(N + 1) * 4);
    int*   cursor   = (int*)alloc((size_t)N * 4);
    int*   elist    = (int*)alloc((size_t)E * 4);

    // init + CSR build (d_ws is re-poisoned before every call)
    hipMemsetAsync(deg, 0, (size_t)N * 4, stream);
    k_split<<<N, 256, 0, stream>>>(h, S, out, N);
    k_deg<<<(E + 255) / 256, 256, 0, stream>>>(receiver, deg, E);
    k_scan<<<1, 1024, 0, stream>>>(deg, rowstart, N);
    hipMemcpyAsync(cursor, rowstart, (size_t)N * 4, hipMemcpyDeviceToDevice, stream);
    k_scatter<<<(E + 255) / 256, 256, 0, stream>>>(receiver, cursor, elist, E);

    const int gb = (N + 63) / 64;
    const int eb = (N * 64 + 255) / 256;

    for (int l = 0; l < 2; ++l) {
        const float* w1 = mp_w1 + (size_t)l * 257 * 128;
        const float* b1 = mp_b1 + (size_t)l * 128;
        const float* w2 = mp_w2 + (size_t)l * 128 * 128;
        const float* b2 = mp_b2 + (size_t)l * 128;
        // Xs = S @ w1[0:128]
        gemm128<0, 0><<<gb, 256, 0, stream>>>(S, w1, nullptr, nullptr, Xs, N);
        // Xrb = S @ w1[128:256] + b1
        gemm128<0, 0><<<gb, 256, 0, stream>>>(S, w1 + 128 * 128, b1, nullptr, Xrb, N);
        // P[r] = sum_e silu(Xs[s] + Xrb[r] + len * w1[256])
        k_edge<<<eb, 256, 0, stream>>>(Xs, Xrb, w1 + 256 * 128, elen, sender, elist,
                                       rowstart, P, N);
        // S += P @ w2 + deg * b2
        gemm128<1, 0><<<gb, 256, 0, stream>>>(P, w2, b2, deg, S, N);
    }

    // node update: T = silu(S@nu_w1 + nu_b1); U = T@nu_w2 + nu_b2; out[:, :128] = S + U
    gemm128<0, 1><<<gb, 256, 0, stream>>>(S, nu_w1, nu_b1, nullptr, Xs, N);
    gemm128<0, 0><<<gb, 256, 0, stream>>>(Xs, nu_w2, nu_b2, nullptr, Xrb, N);
    k_final<<<N, 128, 0, stream>>>(S, Xrb, out, N);
}

// Round 2
// 925.268 us; speedup vs baseline: 1.4637x; 1.4637x over previous
//
#include <hip/hip_runtime.h>
#include <hip/hip_fp16.h>

// FlashACE: 2-layer edge-MLP message passing + node update, N=50000, E=1.6M, HID=128.
//   msgs = silu([S[s],S[r],len] @ w1 + b1) @ w2 + b2 ; agg = segsum(msgs, r)
//   =>  Xs = S@w1[0:128], Xrb = S@w1[128:256] + b1          (node GEMMs, fp16 tables)
//       P[r] = sum_e silu(Xs[s_e] + Xrb[r] + len_e*w1[256]) (edge pass, CSR, no atomics)
//       S += P@w2 + deg*b2                                  (node GEMM, fp32 trunk)
// Edge pass v2: CSR-ordered (sender,len) payload written at scatter time (kills the
// elist->sender dependent chain + random 4B reads); lanes preload 64 payloads and
// __shfl-broadcast; Xs/Xrb gathered as fp16 (halves random HBM traffic).

#define NFEAT 224
#define HID 128

__device__ __forceinline__ float silu_f(float x) {
    float e = __expf(-x);
    return x * __builtin_amdgcn_rcpf(1.0f + e);
}

// ---------------- split: h -> S (first 128 cols), rest -> d_out cols 128..223
__global__ void k_split(const float* __restrict__ h, float* __restrict__ S,
                        float* __restrict__ out, int N) {
    int n = blockIdx.x;
    int j = threadIdx.x;
    if (n >= N || j >= NFEAT) return;
    float v = h[(size_t)n * NFEAT + j];
    if (j < HID) S[(size_t)n * HID + j] = v;
    else out[(size_t)n * NFEAT + j] = v;
}

// ---------------- CSR build
__global__ void k_deg(const int* __restrict__ recv, int* __restrict__ deg, int E) {
    int i = blockIdx.x * blockDim.x + threadIdx.x;
    if (i < E) atomicAdd(&deg[recv[i]], 1);
}

__global__ void k_scan(const int* __restrict__ deg, int* __restrict__ rowstart, int N) {
    __shared__ int ps[1024];
    int t = threadIdx.x;
    int C = (N + 1023) / 1024;
    int lo = t * C;
    int hi = lo + C; if (hi > N) hi = N;
    int s = 0;
    for (int i = lo; i < hi; ++i) s += deg[i];
    ps[t] = s;
    __syncthreads();
    for (int off = 1; off < 1024; off <<= 1) {
        int add = (t >= off) ? ps[t - off] : 0;
        __syncthreads();
        ps[t] += add;
        __syncthreads();
    }
    int run = (t == 0) ? 0 : ps[t - 1];
    for (int i = lo; i < hi; ++i) { rowstart[i] = run; run += deg[i]; }
    if (t == 1023) rowstart[N] = ps[1023];
}

// scatter edge payload (sender, len) into CSR order — one int2 store per edge
__global__ void k_scatter(const int* __restrict__ recv, const int* __restrict__ sender,
                          const float* __restrict__ elen, int* __restrict__ cursor,
                          int2* __restrict__ epack, int E) {
    int i = blockIdx.x * blockDim.x + threadIdx.x;
    if (i < E) {
        int pos = atomicAdd(&cursor[recv[i]], 1);
        epack[pos] = make_int2(sender[i], __float_as_int(elen[i]));
    }
}

// ---------------- fp32 GEMM, K=N=128. C[M,128] = op(A[M,128] @ W[128,128] + bias*scale)
// BM=128, 256 threads, 8x8 thread tile split as (4 rows, +64) x (4 cols, +64) so all
// inner LDS reads are <=2-way bank conflicts (free).
template <int ACC, int SILU, int OUT_HALF>
__launch_bounds__(256, 2)
__global__ void gemm128b(const float* __restrict__ A, const float* __restrict__ W,
                         const float* __restrict__ bias, const int* __restrict__ rowscale,
                         void* __restrict__ Cout, int M) {
    __shared__ float As[128][20];   // stride 80B: rows 4 apart -> 2-way, 16B aligned
    __shared__ float Ws[16][128];
    const int tid = threadIdx.x;
    const int tx = tid & 15;        // col group: cols tx*4..+3 and +64
    const int ty = tid >> 4;        // row group: rows ty*4..+3 and +64
    const int row0 = blockIdx.x * 128;
    const int colA = tx * 4;
    const int rowA = ty * 4;
    float acc[2][4][8];             // [rowhalf][rr][colhalf*4+cc]
#pragma unroll
    for (int a = 0; a < 2; ++a)
#pragma unroll
        for (int r = 0; r < 4; ++r)
#pragma unroll
            for (int c = 0; c < 8; ++c) acc[a][r][c] = 0.0f;

    for (int kc = 0; kc < 128; kc += 16) {
        __syncthreads();
        {   // stage A chunk 128x16
            int r = tid >> 2;
            int kq = (tid & 3) * 4;
#pragma unroll
            for (int rr = 0; rr < 2; ++rr) {
                int row = r + rr * 64;
                int gr = row0 + row;
                float4 v = make_float4(0.f, 0.f, 0.f, 0.f);
                if (gr < M) v = *(const float4*)(A + (size_t)gr * 128 + kc + kq);
                *(float4*)(&As[row][kq]) = v;
            }
        }
        {   // stage W chunk 16x128
#pragma unroll
            for (int q = tid; q < 512; q += 256) {
                int r = q >> 5;
                int c4 = (q & 31) * 4;
                *(float4*)(&Ws[r][c4]) = *(const float4*)(W + (size_t)(kc + r) * 128 + c4);
            }
        }
        __syncthreads();
#pragma unroll
        for (int k4 = 0; k4 < 16; k4 += 4) {
            float4 wlo[4], whi[4];
#pragma unroll
            for (int kk = 0; kk < 4; ++kk) {
                wlo[kk] = *(const float4*)(&Ws[k4 + kk][colA]);
                whi[kk] = *(const float4*)(&Ws[k4 + kk][colA + 64]);
            }
#pragma unroll
            for (int h = 0; h < 2; ++h) {
#pragma unroll
                for (int rr = 0; rr < 4; ++rr) {
                    float4 a = *(const float4*)(&As[rowA + h * 64 + rr][k4]);
                    float* ac = acc[h][rr];
                    ac[0] += a.x * wlo[0].x + a.y * wlo[1].x + a.z * wlo[2].x + a.w * wlo[3].x;
                    ac[1] += a.x * wlo[0].y + a.y * wlo[1].y + a.z * wlo[2].y + a.w * wlo[3].y;
                    ac[2] += a.x * wlo[0].z + a.y * wlo[1].z + a.z * wlo[2].z + a.w * wlo[3].z;
                    ac[3] += a.x * wlo[0].w + a.y * wlo[1].w + a.z * wlo[2].w + a.w * wlo[3].w;
                    ac[4] += a.x * whi[0].x + a.y * whi[1].x + a.z * whi[2].x + a.w * whi[3].x;
                    ac[5] += a.x * whi[0].y + a.y * whi[1].y + a.z * whi[2].y + a.w * whi[3].y;
                    ac[6] += a.x * whi[0].z + a.y * whi[1].z + a.z * whi[2].z + a.w * whi[3].z;
                    ac[7] += a.x * whi[0].w + a.y * whi[1].w + a.z * whi[2].w + a.w * whi[3].w;
                }
            }
        }
    }

#pragma unroll
    for (int h = 0; h < 2; ++h) {
#pragma unroll
        for (int rr = 0; rr < 4; ++rr) {
            int gr = row0 + rowA + h * 64 + rr;
            if (gr >= M) continue;
            float sc = 1.0f;
            if (rowscale) sc = (float)rowscale[gr];
#pragma unroll
            for (int cb = 0; cb < 2; ++cb) {
                int j = colA + cb * 64;
                float v[4];
#pragma unroll
                for (int c = 0; c < 4; ++c) {
                    v[c] = acc[h][rr][cb * 4 + c];
                    if (bias) v[c] += bias[j + c] * sc;
                    if (SILU) v[c] = silu_f(v[c]);
                }
                if (OUT_HALF) {
                    __half2* Ch = (__half2*)Cout;
                    Ch[((size_t)gr * 128 + j) >> 1]       = __floats2half2_rn(v[0], v[1]);
                    Ch[(((size_t)gr * 128 + j) >> 1) + 1] = __floats2half2_rn(v[2], v[3]);
                } else {
                    float* C = (float*)Cout;
                    size_t idx = (size_t)gr * 128 + j;
                    if (ACC) {
                        C[idx + 0] += v[0]; C[idx + 1] += v[1];
                        C[idx + 2] += v[2]; C[idx + 3] += v[3];
                    } else {
                        *(float4*)(C + idx) = make_float4(v[0], v[1], v[2], v[3]);
                    }
                }
            }
        }
    }
}

// ---------------- edge aggregation: one wave per receiver, fp16 gather, shfl broadcast
__launch_bounds__(256)
__global__ void k_edge(const __half2* __restrict__ Xs, const __half2* __restrict__ Xrb,
                       const float* __restrict__ w1L, const int2* __restrict__ epack,
                       const int* __restrict__ rowstart, float* __restrict__ P, int N) {
    int wid = (blockIdx.x * blockDim.x + threadIdx.x) >> 6;
    int lane = threadIdx.x & 63;
    if (wid >= N) return;
    float2 xr = __half22float2(Xrb[(size_t)wid * 64 + lane]);
    float2 wl = *(const float2*)(w1L + lane * 2);
    float ax = 0.f, ay = 0.f;
    int lo = rowstart[wid], hi = rowstart[wid + 1];
    for (int base = lo; base < hi; base += 64) {
        int idx = base + lane;
        int sv = 0;
        float lv = 0.f;
        if (idx < hi) {
            int2 ev = epack[idx];        // coalesced 8B/lane
            sv = ev.x;
            lv = __int_as_float(ev.y);
        }
        int cnt = hi - base; if (cnt > 64) cnt = 64;
#pragma unroll 4
        for (int k = 0; k < cnt; ++k) {
            int s = __shfl(sv, k, 64);
            float len = __shfl(lv, k, 64);
            float2 x = __half22float2(Xs[(size_t)s * 64 + lane]);  // 256B/row coalesced
            ax += silu_f(x.x + xr.x + len * wl.x);
            ay += silu_f(x.y + xr.y + len * wl.y);
        }
    }
    *(float2*)(P + (size_t)wid * 128 + lane * 2) = make_float2(ax, ay);
}

// ---------------- final: d_out[:, :128] = S + U
__global__ void k_final(const float* __restrict__ S, const float* __restrict__ U,
                        float* __restrict__ out, int N) {
    int n = blockIdx.x;
    int j = threadIdx.x;
    if (n >= N || j >= HID) return;
    size_t si = (size_t)n * 128 + j;
    out[(size_t)n * NFEAT + j] = S[si] + U[si];
}

extern "C" void kernel_launch(void* const* d_in, const int* in_sizes, int n_in,
                              void* d_out, int out_size, void* d_ws, size_t ws_size,
                              hipStream_t stream) {
    const float* h      = (const float*)d_in[0];
    const int*   eidx   = (const int*)d_in[1];
    const float* elen   = (const float*)d_in[2];
    const float* mp_w1  = (const float*)d_in[3];
    const float* mp_b1  = (const float*)d_in[4];
    const float* mp_w2  = (const float*)d_in[5];
    const float* mp_b2  = (const float*)d_in[6];
    const float* nu_w1  = (const float*)d_in[7];
    const float* nu_b1  = (const float*)d_in[8];
    const float* nu_w2  = (const float*)d_in[9];
    const float* nu_b2  = (const float*)d_in[10];
    float* out = (float*)d_out;

    const int N = in_sizes[0] / NFEAT;   // 50000
    const int E = in_sizes[2];           // 1600000
    const int* sender   = eidx;
    const int* receiver = eidx + E;

    char* w = (char*)d_ws;
    auto alloc = [&](size_t bytes) -> char* {
        char* p = w;
        w += (bytes + 255) & ~(size_t)255;
        return p;
    };
    float*  S     = (float*)alloc((size_t)N * 128 * 4);
    float*  P     = (float*)alloc((size_t)N * 128 * 4);
    __half* Xs16  = (__half*)alloc((size_t)N * 128 * 2);
    __half* Xrb16 = (__half*)alloc((size_t)N * 128 * 2);   // contiguous after Xs16
    float*  U     = (float*)Xs16;  // overlay: reused only after edge passes are done
    int2*   epack = (int2*)alloc((size_t)E * 8);
    int*    deg      = (int*)alloc((size_t)N * 4);
    int*    rowstart = (int*)alloc((size_t)(N + 1) * 4);
    int*    cursor   = (int*)alloc((size_t)N * 4);

    hipMemsetAsync(deg, 0, (size_t)N * 4, stream);
    k_split<<<N, 256, 0, stream>>>(h, S, out, N);
    k_deg<<<(E + 255) / 256, 256, 0, stream>>>(receiver, deg, E);
    k_scan<<<1, 1024, 0, stream>>>(deg, rowstart, N);
    hipMemcpyAsync(cursor, rowstart, (size_t)N * 4, hipMemcpyDeviceToDevice, stream);
    k_scatter<<<(E + 255) / 256, 256, 0, stream>>>(receiver, sender, elen, cursor, epack, E);

    const int gb = (N + 127) / 128;
    const int eb = (N * 64 + 255) / 256;

    for (int l = 0; l < 2; ++l) {
        const float* w1 = mp_w1 + (size_t)l * 257 * 128;
        const float* b1 = mp_b1 + (size_t)l * 128;
        const float* w2 = mp_w2 + (size_t)l * 128 * 128;
        const float* b2 = mp_b2 + (size_t)l * 128;
        // Xs16 = half(S @ w1[0:128]) ; Xrb16 = half(S @ w1[128:256] + b1)
        gemm128b<0, 0, 1><<<gb, 256, 0, stream>>>(S, w1, nullptr, nullptr, Xs16, N);
        gemm128b<0, 0, 1><<<gb, 256, 0, stream>>>(S, w1 + 128 * 128, b1, nullptr, Xrb16, N);
        // P[r] = sum_e silu(Xs[s] + Xrb[r] + len * w1[256])
        k_edge<<<eb, 256, 0, stream>>>((const __half2*)Xs16, (const __half2*)Xrb16,
                                       w1 + 256 * 128, epack, rowstart, P, N);
        // S += P @ w2 + deg * b2
        gemm128b<1, 0, 0><<<gb, 256, 0, stream>>>(P, w2, b2, deg, S, N);
    }

    // node update: T = silu(S@nu_w1 + nu_b1) -> P ; U = T@nu_w2 + nu_b2 ; out = S + U
    gemm128b<0, 1, 0><<<gb, 256, 0, stream>>>(S, nu_w1, nu_b1, nullptr, P, N);
    gemm128b<0, 0, 0><<<gb, 256, 0, stream>>>(P, nu_w2, nu_b2, nullptr, U, N);
    k_final<<<N, 128, 0, stream>>>(S, U, out, N);
}